// Round 13
// baseline (142.161 us; speedup 1.0000x reference)
//
#include <hip/hip_runtime.h>
#include <math.h>

#define S_LEN 2048
#define BSZ 2
#define DM 512
#define NH 8
#define HD 64
#define RTOT (S_LEN*BSZ)             // 4096 rows, row r = s*BSZ + b
#define T_KEEP 32
#define ROW0 ((S_LEN - T_KEEP)*BSZ)  // 4032

typedef __attribute__((ext_vector_type(8))) _Float16 half8;
typedef __attribute__((ext_vector_type(4))) float floatx4;

__device__ __forceinline__ void gld16(const void* g, void* l) {
    __builtin_amdgcn_global_load_lds((const __attribute__((address_space(1))) void*)g,
                                     (__attribute__((address_space(3))) void*)l, 16, 0, 0);
}

__device__ __forceinline__ short cvt1(float v) {
    _Float16 h = (_Float16)v;
    return __builtin_bit_cast(short, h);
}

// ---- Kernel 0: fragment-major fp16 re-tiling (LDS transpose) + bg fill --------
// Fragment piece layout: ((tile*16 + kc)*64 + lane)*16B, lane = lk8*16 + lrow,
// holding elem [tile_row=lrow][k = kc*32 + lk8*8 .. +8] as 8 fp16.
// blocks 0..255: x tiles (rt). 256..319: W tiles (h,jh,t; t:0,1=q 2,3=k sub16).
// blocks 320..831: background fill of out rows < ROW0.
__global__ __launch_bounds__(256) void convert2(
    const float* __restrict__ x, const float* __restrict__ Wq,
    const float* __restrict__ Wk, const float* __restrict__ bo,
    short* __restrict__ xfrag, short* __restrict__ wfrag, float* __restrict__ out)
{
    __shared__ short sm[8192];   // 16 KB: one 16x512 tile in fragment order
    const int bx = blockIdx.x;
    const int tid = threadIdx.x;
    if (bx >= 320) {
        int g = (bx - 320)*256 + tid;
        const float4* b4 = (const float4*)bo;
        float4* o4 = (float4*)out;
        const int fill4 = ROW0*DM/4;
        for (int i = g; i < fill4; i += 512*256) o4[i] = b4[i & 127];
        return;
    }
    const float* src;
    short* dst;
    if (bx < 256) {
        src = x + (size_t)bx*16*DM;
        dst = xfrag + (size_t)bx*16*DM;          // 8192 shorts per tile
    } else {
        int wt = bx - 256;
        int h = wt >> 3, jh = (wt >> 2) & 1, t = wt & 3;
        int m = t >> 1, sub = t & 1;
        const float* W = m ? Wk : Wq;
        src = W + (size_t)(h*HD + jh*32 + sub*16)*DM;
        dst = wfrag + (size_t)((h*2 + jh)*64 + t*16)*512;
    }
    #pragma unroll
    for (int it = 0; it < 8; ++it) {
        int f4 = it*256 + tid;
        int row = f4 >> 7, k4 = f4 & 127;        // coalesced float4 reads
        float4 v = ((const float4*)src)[row*128 + k4];
        short4 hv;
        hv.x = cvt1(v.x); hv.y = cvt1(v.y); hv.z = cvt1(v.z); hv.w = cvt1(v.w);
        int kc = k4 >> 3, lk8 = (k4 >> 1) & 3, ho = (k4 & 1)*4;
        *(short4*)&sm[(kc*64 + lk8*16 + row)*8 + ho] = hv;
    }
    __syncthreads();
    #pragma unroll
    for (int it = 0; it < 4; ++it) {             // coalesced 16B writes
        int p = it*256 + tid;
        uint4 v = *(const uint4*)&sm[p*8];
        *(uint4*)&dst[p*8] = v;
    }
}

// ---- Kernel 1: fp16 MFMA q,k GEMM -> raw sigma scores (+qsel) -----------------
// grid (32 rowchunks, 8 heads, 2 j-halves): block = 128 rows x 32 j's (q&k).
// B (64 fragment chunks = 64KB) staged via coalesced gld16 ONCE (one barrier).
// A fragments straight from xfrag, coalesced (base + lane*16). No main-loop
// barriers; sig/qsel direct stores (no atomics anywhere).
__global__ __launch_bounds__(256, 2) void qk_gemm(
    const short* __restrict__ xfrag, const short* __restrict__ wfrag,
    const float* __restrict__ bq, const float* __restrict__ bk,
    float* __restrict__ sig, float* __restrict__ qsel)
{
    __shared__ __align__(16) char smem[65536];

    const int tid  = threadIdx.x;
    const int w    = tid >> 6;
    const int lane = tid & 63;
    const int lrow = lane & 15;
    const int lk8  = lane >> 4;
    const int rc   = blockIdx.x;
    const int h    = blockIdx.y;
    const int jh   = blockIdx.z;

    // stage B: wave w stages chunks [w*16, w*16+16), fully coalesced
    {
        const short* src = wfrag + ((size_t)(h*2 + jh)*64 + w*16)*512 + lane*8;
        for (int ci = 0; ci < 16; ++ci)
            gld16(src + ci*512, smem + (w*16 + ci)*1024);
    }
    __syncthreads();

    const float bq0 = bq[h*HD + jh*32 + lrow];
    const float bq1 = bq[h*HD + jh*32 + 16 + lrow];
    const float bk0 = bk[h*HD + jh*32 + lrow];
    const float bk1 = bk[h*HD + jh*32 + 16 + lrow];

    #pragma unroll
    for (int nn = 0; nn < 2; ++nn) {
        const int rt = rc*8 + w + nn*4;          // row-tile (16 rows)
        const int rbase = rt*16;

        half8 A[16];
        const short* pa = xfrag + (size_t)rt*8192 + lane*8;
        #pragma unroll
        for (int kc = 0; kc < 16; ++kc)
            A[kc] = *(const half8*)(pa + kc*512);

        floatx4 aq0 = (floatx4)0.f, aq1 = (floatx4)0.f;
        floatx4 ak0 = (floatx4)0.f, ak1 = (floatx4)0.f;
        #pragma unroll
        for (int kc = 0; kc < 16; ++kc) {
            half8 b0 = *(const half8*)(smem + ( 0 + kc)*1024 + lane*16);
            half8 b1 = *(const half8*)(smem + (16 + kc)*1024 + lane*16);
            half8 b2 = *(const half8*)(smem + (32 + kc)*1024 + lane*16);
            half8 b3 = *(const half8*)(smem + (48 + kc)*1024 + lane*16);
            aq0 = __builtin_amdgcn_mfma_f32_16x16x32_f16(A[kc], b0, aq0, 0, 0, 0);
            aq1 = __builtin_amdgcn_mfma_f32_16x16x32_f16(A[kc], b1, aq1, 0, 0, 0);
            ak0 = __builtin_amdgcn_mfma_f32_16x16x32_f16(A[kc], b2, ak0, 0, 0, 0);
            ak1 = __builtin_amdgcn_mfma_f32_16x16x32_f16(A[kc], b3, ak1, 0, 0, 0);
        }

        #pragma unroll
        for (int r = 0; r < 4; ++r) {
            float q0 = aq0[r] + bq0, q1 = aq1[r] + bq1;
            float k0 = ak0[r] + bk0, k1 = ak1[r] + bk1;
            float p = q0*k0 + q1*k1;
            p += __shfl_xor(p, 1, 64);
            p += __shfl_xor(p, 2, 64);
            p += __shfl_xor(p, 4, 64);
            p += __shfl_xor(p, 8, 64);
            int row = rbase + lk8*4 + r;
            if (lrow == 0) sig[((size_t)jh*NH + h)*RTOT + row] = p;
            if (((row >> 1) & 63) == 63) {
                int b  = row & 1;
                int wi = row >> 7;
                float* qd = &qsel[((size_t)(b*NH + h)*T_KEEP + wi)*64];
                qd[jh*32 + lrow]      = q0;
                qd[jh*32 + 16 + lrow] = q1;
            }
        }
    }
}

// ---- Kernel 2: sigma = sigmoid((sig0+sig1)*scale); sbar; Ssum -----------------
// grid 32: b = bx&1, col-chunk cc = (bx>>1)*32. Direct stores, no atomics.
__global__ __launch_bounds__(256) void sbark(
    const float* __restrict__ x, const float* __restrict__ sig,
    const float* __restrict__ beta, float* __restrict__ sbar,
    float* __restrict__ Ssum)
{
    __shared__ float ss[256*8];     // [s_local][h]
    __shared__ float s_red[2048];   // [sgrp*32+col][h]
    const int tid = threadIdx.x;
    const int b = blockIdx.x & 1;
    const int cc = (blockIdx.x >> 1)*32;
    const int col = tid & 31, sgrp = tid >> 5;
    const int hld = tid & 7, sld = tid >> 3;
    const float is = 1.0f / (8.0f * expf(beta[hld]));

    float a8[8];
    #pragma unroll
    for (int hh = 0; hh < 8; ++hh) a8[hh] = 0.f;
    float tsum = 0.f;

    for (int scn = 0; scn < 8; ++scn) {
        const int s0 = scn*256;
        #pragma unroll
        for (int j = 0; j < 8; ++j) {
            int sl = sld + 32*j;
            int s = s0 + sl;
            float raw = sig[(size_t)hld*RTOT + s*2 + b]
                      + sig[(size_t)(NH + hld)*RTOT + s*2 + b];
            float sv = 1.0f / (1.0f + expf(-raw * is));
            ss[sl*8 + hld] = sv;
            tsum += sv;
        }
        __syncthreads();
        for (int j = 0; j < 32; ++j) {
            int sl = sgrp + j*8;
            float xv = x[(size_t)((s0 + sl)*2 + b)*DM + cc + col];
            #pragma unroll
            for (int hh = 0; hh < 8; ++hh) a8[hh] += ss[sl*8 + hh] * xv;
        }
        __syncthreads();
    }
    #pragma unroll
    for (int hh = 0; hh < 8; ++hh) s_red[(sgrp*32 + col)*8 + hh] = a8[hh];
    __syncthreads();
    {
        int hh = tid >> 5, c2 = tid & 31;
        float a = 0.f;
        #pragma unroll
        for (int sg = 0; sg < 8; ++sg) a += s_red[(sg*32 + c2)*8 + hh];
        sbar[(size_t)(b*NH + hh)*DM + cc + c2] = a;
    }
    if (cc == 0) {
        __syncthreads();
        s_red[tid] = tsum;
        __syncthreads();
        if (tid < 8) {
            float t = 0.f;
            for (int i = tid; i < 256; i += 8) t += s_red[i];
            Ssum[b*NH + tid] = t;
        }
    }
}

// ---- Kernel 3: kbar/vbar = W*sbar + b*S; coef softmax; G row ------------------
__global__ __launch_bounds__(256) void headk(
    const float* __restrict__ qsel, const float* __restrict__ beta,
    const float* __restrict__ sbar, const float* __restrict__ Ssum,
    const float* __restrict__ Wk, const float* __restrict__ bk,
    const float* __restrict__ Wv, const float* __restrict__ bv,
    const float* __restrict__ Wo,
    float* __restrict__ coef, float* __restrict__ G)
{
    const int z = blockIdx.x;
    const int h = z & 7;
    const int tid = threadIdx.x;

    __shared__ float s_sb[DM];
    __shared__ float s_red[64][4];
    __shared__ float s_kb[64], s_vb[64];
    __shared__ float s_part[T_KEEP][8];
    __shared__ float s_gp[64][4];

    s_sb[tid]       = sbar[z*DM + tid];
    s_sb[tid + 256] = sbar[z*DM + 256 + tid];
    __syncthreads();
    const float S = Ssum[z];

    {
        int j = tid >> 2, kp = tid & 3;
        const float* wr = &Wk[(size_t)(h*HD + j)*DM + kp*128];
        float a = 0.f;
        #pragma unroll
        for (int k = 0; k < 128; k += 4) {
            float4 w4 = *(const float4*)&wr[k];
            int k0 = kp*128 + k;
            a += w4.x*s_sb[k0] + w4.y*s_sb[k0+1] + w4.z*s_sb[k0+2] + w4.w*s_sb[k0+3];
        }
        s_red[j][kp] = a;
    }
    __syncthreads();
    if (tid < 64) s_kb[tid] = s_red[tid][0]+s_red[tid][1]+s_red[tid][2]+s_red[tid][3]
                              + bk[h*HD + tid]*S;
    __syncthreads();
    {
        int j = tid >> 2, kp = tid & 3;
        const float* wr = &Wv[(size_t)(h*HD + j)*DM + kp*128];
        float a = 0.f;
        #pragma unroll
        for (int k = 0; k < 128; k += 4) {
            float4 w4 = *(const float4*)&wr[k];
            int k0 = kp*128 + k;
            a += w4.x*s_sb[k0] + w4.y*s_sb[k0+1] + w4.z*s_sb[k0+2] + w4.w*s_sb[k0+3];
        }
        s_red[j][kp] = a;
    }
    __syncthreads();
    if (tid < 64) s_vb[tid] = s_red[tid][0]+s_red[tid][1]+s_red[tid][2]+s_red[tid][3]
                              + bv[h*HD + tid]*S;
    __syncthreads();

    {
        int wi = tid >> 3, jg = tid & 7;
        const float* qrow = &qsel[((size_t)z*T_KEEP + wi)*64 + jg*8];
        float4 q1 = *(const float4*)qrow;
        float4 q2 = *(const float4*)(qrow + 4);
        int j0 = jg*8;
        float p = q1.x*s_kb[j0] + q1.y*s_kb[j0+1] + q1.z*s_kb[j0+2] + q1.w*s_kb[j0+3]
                + q2.x*s_kb[j0+4] + q2.y*s_kb[j0+5] + q2.z*s_kb[j0+6] + q2.w*s_kb[j0+7];
        s_part[wi][jg] = p;
    }
    __syncthreads();
    if (tid < T_KEEP) {
        float sc = 0.f;
        #pragma unroll
        for (int gg = 0; gg < 8; ++gg) sc += s_part[tid][gg];
        sc *= 1.0f / (8.0f * expf(beta[h]));
        float m = sc;
        #pragma unroll
        for (int off = 16; off > 0; off >>= 1) m = fmaxf(m, __shfl_xor(m, off, 64));
        m = fmaxf(m, 0.f);                       // sink logit = 0
        float e = expf(sc - m);
        float d = e;
        #pragma unroll
        for (int off = 16; off > 0; off >>= 1) d += __shfl_xor(d, off, 64);
        d += expf(-m);                           // sink term
        float c = e / d;
        if (tid == T_KEEP-1) c += 1.0f;          // iter-0 contribution
        coef[z*T_KEEP + tid] = c;
    }

    const int cq = tid >> 2;
    const int jg = tid & 3;
    #pragma unroll
    for (int it = 0; it < 8; ++it) {
        int c = it*64 + cq;
        const float* wrow = &Wo[(size_t)c*DM + h*HD + jg*16];
        float a = 0.f;
        #pragma unroll
        for (int jj = 0; jj < 16; jj += 4) {
            float4 wv = *(const float4*)&wrow[jj];
            int j0 = jg*16 + jj;
            a += wv.x*s_vb[j0] + wv.y*s_vb[j0+1] + wv.z*s_vb[j0+2] + wv.w*s_vb[j0+3];
        }
        s_gp[cq][jg] = a;
        __syncthreads();
        if (tid < 64)
            G[(size_t)z*DM + it*64 + tid] = s_gp[tid][0] + s_gp[tid][1] + s_gp[tid][2] + s_gp[tid][3];
        __syncthreads();
    }
}

// ---- Kernel 4: output rows from coef x G --------------------------------------
__global__ __launch_bounds__(256) void outk3(
    const float* __restrict__ coef, const float* __restrict__ G,
    const float* __restrict__ bo, float* __restrict__ out)
{
    const int a = blockIdx.x;
    const int b = a & 1;
    const int wi = a >> 1;
    const int tid = threadIdx.x;
    __shared__ float s_cf[NH];
    if (tid < NH) s_cf[tid] = coef[(b*NH + tid)*T_KEEP + wi];
    __syncthreads();
    for (int c = tid; c < DM; c += 256) {
        float v = bo[c];
        #pragma unroll
        for (int h = 0; h < NH; ++h)
            v += s_cf[h] * G[(size_t)(b*NH + h)*DM + c];
        out[(size_t)(ROW0 + a)*DM + c] = v;
    }
}

extern "C" void kernel_launch(void* const* d_in, const int* in_sizes, int n_in,
                              void* d_out, int out_size, void* d_ws, size_t ws_size,
                              hipStream_t stream) {
    const float* x    = (const float*)d_in[0];
    const float* Wq   = (const float*)d_in[1];
    const float* bq   = (const float*)d_in[2];
    const float* Wk   = (const float*)d_in[3];
    const float* bk   = (const float*)d_in[4];
    const float* Wv   = (const float*)d_in[5];
    const float* bv   = (const float*)d_in[6];
    const float* Wo   = (const float*)d_in[7];
    const float* bo   = (const float*)d_in[8];
    const float* beta = (const float*)d_in[9];

    char* ws = (char*)d_ws;
    float* sig   = (float*)(ws + 0);          // 256 KB [jh][h][4096]
    float* qsel  = (float*)(ws + 262144);     // 128 KB
    float* sbar  = (float*)(ws + 393216);     //  32 KB [z][512]
    float* Ssum  = (float*)(ws + 425984);     //  64 B
    float* coef  = (float*)(ws + 426240);     //   2 KB
    float* G     = (float*)(ws + 428288);     //  32 KB
    short* xfrag = (short*)(ws + 461056);     //   4 MB (fragment-major)
    short* wfrag = (short*)(ws + 461056 + 4194304);  // 1 MB
    float* out   = (float*)d_out;

    convert2<<<832, 256, 0, stream>>>(x, Wq, Wk, bo, xfrag, wfrag, out);
    dim3 g1(32, NH, 2);
    qk_gemm<<<g1, 256, 0, stream>>>(xfrag, wfrag, bq, bk, sig, qsel);
    sbark<<<32, 256, 0, stream>>>(x, sig, beta, sbar, Ssum);
    headk<<<16, 256, 0, stream>>>(qsel, beta, sbar, Ssum, Wk, bk, Wv, bv, Wo, coef, G);
    outk3<<<64, 256, 0, stream>>>(coef, G, bo, out);
}